// Round 9
// baseline (190.177 us; speedup 1.0000x reference)
//
#include <hip/hip_runtime.h>
#include <hip/hip_fp16.h>
#include <math.h>

#define HW 4096
#define NN 32
#define W68 68
#define RSTR 2192   // window row stride in bytes; 2192 % 128 == 16 so row
                    // jitter rotates the LDS bank group (2176 was 17*128 -> 32-way)

typedef __attribute__((ext_vector_type(8))) _Float16 f16x8;
typedef __attribute__((ext_vector_type(2))) _Float16 h2;
typedef __attribute__((ext_vector_type(4))) float f32x4;

// f32 -> f16 bits, RNE (single v_cvt_f16_f32)
__device__ inline unsigned short hbits(float a) {
    _Float16 h = (_Float16)a;
    unsigned short u;
    __builtin_memcpy(&u, &h, 2);
    return u;
}
// packed f32x2 -> f16x2, RTZ, one v_cvt_pkrtz_f16_f32
__device__ inline unsigned hpack(float a, float b) {
    auto p = __builtin_amdgcn_cvt_pkrtz(a, b);
    unsigned u;
    __builtin_memcpy(&u, &p, 4);
    return u;
}

// swizzled byte offset within one window row: slot = 16 bytes of 8 channels
// (c8 half) at column x. XOR of bit4 with x-bit2 spreads the 32B-stride
// column walk across bank groups.
__device__ inline int xsw(int x, int c8) {
    return ((x << 5) | (c8 << 4)) ^ (((x >> 2) & 1) << 4);
}

// ---------------------------------------------------------------------------
// Kernel W: build the B-fragment-permuted weight buffer wperm (f16).
//   wperm[g*7680 + which*2560 + ((kp*4+q)*16+nn)*8 + j],
//   which: 0=w_dc, 1=w_off rows 0..15, 2=w_off rows 16..17,
//   k=q*8+j -> c=k&15, tap=kp*2+(k>>4); zero for tap>=9.
// ---------------------------------------------------------------------------
__global__ __launch_bounds__(256) void wperm_build(const float* __restrict__ w_off,
                                                   const float* __restrict__ w_dc,
                                                   unsigned short* __restrict__ wperm)
{
    int idx = blockIdx.x * 256 + threadIdx.x;    // < 30720
    int g = idx / 7680;
    int r3 = idx - g * 7680;
    int which = r3 / 2560;
    int r = r3 - which * 2560;
    int j = r & 7;
    int rest = r >> 3;
    int nn_ = rest & 15; rest >>= 4;
    int q_ = rest & 3, kp_ = rest >> 2;
    int k = q_ * 8 + j;
    int c = k & 15, tt = kp_ * 2 + (k >> 4);
    float v = 0.f;
    if (tt < 9) {
        if (which == 0)      v = w_dc[(g * 16 + nn_) * 144 + c * 9 + tt];
        else if (which == 1) v = w_off[(g * 18 + nn_) * 144 + c * 9 + tt];
        else if (nn_ < 2)    v = w_off[(g * 18 + 16 + nn_) * 144 + c * 9 + tt];
    }
    wperm[idx] = hbits(v);
}

// ---------------------------------------------------------------------------
// Kernel F: fused offset-conv + deformable conv, all-f16 datapath.
// 512-THREAD BLOCKS, two independent wave-groups (cc = wv>>2) sharing one
// 13-row f16 x-window (rows R0-2..R0+10, XOR-swizzled, 28.5KB). Group cc
// processes chunk chunk2*2+cc with code IDENTICAL per-wave to the R7 kernel
// (no cross-chunk register liveness -> no spills, unlike the R8 chunk-loop).
// LDS = 49.2KB -> 3 blocks/CU x 8 waves = 24 waves/CU (R7: 20).
// Window-build global traffic halves (1.625 vs 2.25 row-loads/output-row).
// Bilinear as packed v_pk_fma_f16; MFMA 16x16x32_f16; LDS-staged coalesced
// f16 epilogue. Rare out-of-window lanes fall back to exact fp32-x gathers
// converted with the same cvt_pkrtz (bit-identical).
// ---------------------------------------------------------------------------
__global__ __launch_bounds__(512, 6) void fused_conv(const float* __restrict__ x,
                                                     const unsigned short* __restrict__ wperm,
                                                     const float* __restrict__ b_off,
                                                     const float* __restrict__ b_dc,
                                                     unsigned short* __restrict__ outpre)
{
    __shared__ __attribute__((aligned(16))) unsigned short xwin[14248];        // 13*2192 B
    __shared__ __attribute__((aligned(16))) unsigned short off_lds[2 * 5120];  // 2 x (256x20); also epi buf

    int bhw = blockIdx.x;
    int bx = (bhw & 7) * 128 + (bhw >> 3);       // XCD swizzle (1024%8==0, bijective)
    int n = bx >> 5, g = (bx >> 3) & 3, chunk2 = bx & 7;
    int t = threadIdx.x;
    int lane = t & 63, wv = t >> 6;              // wv in [0,8)
    int cc = wv >> 2, lv = wv & 3;               // wave-group (chunk) / local wave
    int nn = lane & 15, q = lane >> 4;
    int t2 = q >> 1, chh = q & 1;
    int R0 = chunk2 * 8;                         // h of block's first output row

    const unsigned short* wpg = wperm + g * 7680;
    const float* xgbase = x + (size_t)(n * 64 + g * 16) * HW;
    unsigned short* offp = off_lds + cc * 5120;  // this group's offset rows

    // ---- build 13-row window from x: wave w builds rows w and w+8 (w<5).
    {
        int col = lane;                          // x-slot = col+2
        #pragma unroll
        for (int rr = 0; rr < 2; rr++) {
            int r = wv + rr * 8;
            if (r < 13) {                        // wave-uniform
                int h = R0 + r - 2;
                uint4 lo = {0, 0, 0, 0}, hi = {0, 0, 0, 0};
                if ((unsigned)h < 64u) {         // wave-uniform branch
                    const float* xp = xgbase + h * 64 + col;
                    float v[16];
                    #pragma unroll
                    for (int c = 0; c < 16; c++) v[c] = xp[(size_t)c * HW];
                    lo.x = hpack(v[0], v[1]);  lo.y = hpack(v[2], v[3]);
                    lo.z = hpack(v[4], v[5]);  lo.w = hpack(v[6], v[7]);
                    hi.x = hpack(v[8], v[9]);  hi.y = hpack(v[10], v[11]);
                    hi.z = hpack(v[12], v[13]); hi.w = hpack(v[14], v[15]);
                }
                *(uint4*)((char*)xwin + r * RSTR + xsw(col + 2, 0)) = lo;
                *(uint4*)((char*)xwin + r * RSTR + xsw(col + 2, 1)) = hi;
            }
        }
        if (t < 104) {                           // w-halo: cols {0,1,66,67} x 13 rows x 2 c8
            int r = t >> 3, rem = t & 7;
            int xc = rem >> 1, c8 = rem & 1;
            int xx = xc < 2 ? xc : xc + 64;
            uint4 z = {0, 0, 0, 0};
            *(uint4*)((char*)xwin + r * RSTR + xsw(xx, c8)) = z;
        }
    }

    // per-s constants (R7-identical, lv in place of wv)
    int pls[4], xbs[4]; float fx_[4];
    #pragma unroll
    for (int s = 0; s < 4; s++) {
        int pl = (lv * 4 + s) * 16 + nn;
        pls[s] = pl;
        int w = ((lv * 4 + s) & 3) * 16 + nn;
        fx_[s] = (float)(w - 1);
        xbs[s] = w + 1;                          // window col of w
    }
    int rwbase = 4 * cc + lv + 1;                // window row of (h-1)
    float fybase = (float)(R0 + 4 * cc + lv - 1);

    __syncthreads();

    // ================= Phase 1: offset conv (window reads) =================
    {
        f16x8 pb0[5], pb1[5];                    // scoped: dead after phase 1
        #pragma unroll
        for (int kp = 0; kp < 5; kp++) {
            int fo = ((kp * 4 + q) * 16 + nn) * 8;
            pb0[kp] = *(const f16x8*)(wpg + 2560 + fo);
            pb1[kp] = *(const f16x8*)(wpg + 5120 + fo);
        }

        f32x4 acc0[4], acc1[4];
        float bv0 = b_off[g * 18 + nn];
        float bv1 = (nn < 2) ? b_off[g * 18 + 16 + nn] : 0.f;
        #pragma unroll
        for (int s = 0; s < 4; s++)
            #pragma unroll
            for (int r = 0; r < 4; r++) { acc0[s][r] = bv0; acc1[s][r] = bv1; }

        uint4 xv[2][4];
        auto stage1 = [&](int kp) {
            int ki = t2 ? (2 * kp + 1) / 3 : (2 * kp) / 3;
            int kj = t2 ? (2 * kp + 1) % 3 : (2 * kp) % 3;
            int sl = kp & 1;
            #pragma unroll
            for (int s = 0; s < 4; s++) {
                int adr = (rwbase + ki) * RSTR + xsw(xbs[s] + kj, chh);
                xv[sl][s] = *(const uint4*)((const char*)xwin + adr);
            }
        };
        stage1(0);
        #pragma unroll
        for (int kp = 0; kp < 5; kp++) {
            if (kp < 4) stage1(kp + 1);
            __builtin_amdgcn_sched_barrier(0);
            int sl = kp & 1;
            #pragma unroll
            for (int s = 0; s < 4; s++) {
                f16x8 af = *(f16x8*)&xv[sl][s];
                acc0[s] = __builtin_amdgcn_mfma_f32_16x16x32_f16(af, pb0[kp], acc0[s], 0, 0, 0);
                acc1[s] = __builtin_amdgcn_mfma_f32_16x16x32_f16(af, pb1[kp], acc1[s], 0, 0, 0);
            }
        }

        #pragma unroll
        for (int s = 0; s < 4; s++) {
            int pl = (lv * 4 + s) * 16 + q * 4;
            #pragma unroll
            for (int r = 0; r < 4; r++) {
                offp[(pl + r) * 20 + nn] = hbits(acc0[s][r]);
                if (nn < 2)
                    offp[(pl + r) * 20 + 16 + nn] = hbits(acc1[s][r]);
            }
        }
        // zero the 2-short row pad (t in [0,512) covers both groups' rows):
        // tap==9 then reads dy=dx=0 (safe in-window addresses) and its
        // wperm B-slots are zero -> exact 0.
        off_lds[t * 20 + 18] = 0;
        off_lds[t * 20 + 19] = 0;
    }

    // phase-2 B-fragments: issue before the barrier, latency hides under it
    f16x8 bwr[5];
    #pragma unroll
    for (int kp = 0; kp < 5; kp++)
        bwr[kp] = *(const f16x8*)(wpg + ((kp * 4 + q) * 16 + nn) * 8);

    __syncthreads();

    // ================= Phase 2: deformable conv (window reads) =============
    f32x4 acc[4];
    float bvd = b_dc[g * 16 + nn];
    #pragma unroll
    for (int s = 0; s < 4; s++)
        #pragma unroll
        for (int r = 0; r < 4; r++) acc[s][r] = bvd;

    uint4 RA[2], RB[2], RC[2], RD[2];
    h2 rwh[2][4];
    int rinw[2], rgy[2], rgx[2];

    // exact fp32-x fallback gather for out-of-window corners (never taken in
    // practice; same cvt_pkrtz as the window build -> bit-identical)
    auto gather_x = [&](int R, int C) -> uint4 {
        uint4 out = {0, 0, 0, 0};
        int h = R - 2, w = C - 2;
        if ((unsigned)h < 64u && (unsigned)w < 64u) {
            const float* xp = xgbase + (size_t)(chh * 8) * HW + h * 64 + w;
            unsigned* o = (unsigned*)&out;
            #pragma unroll
            for (int k = 0; k < 4; k++)
                o[k] = hpack(xp[(size_t)(2 * k) * HW], xp[(size_t)(2 * k + 1) * HW]);
        }
        return out;
    };

    auto stage = [&](int u) {
        int kp = u >> 2, s = u & 3, sl = u & 1;
        int ki = t2 ? (2 * kp + 1) / 3 : (2 * kp) / 3;
        int kj = t2 ? (2 * kp + 1) % 3 : (2 * kp) % 3;
        unsigned uo = *(const unsigned*)&offp[pls[s] * 20 + 4 * kp + 2 * t2];
        h2 oo;
        __builtin_memcpy(&oo, &uo, 4);
        float py = fybase + (float)ki + (float)oo[0];
        float px = fx_[s] + (float)kj + (float)oo[1];
        float y0f = fminf(fmaxf(floorf(py), -2.f), 64.f);
        float x0f = fminf(fmaxf(floorf(px), -2.f), 64.f);
        float ly = py - y0f, lx = px - x0f;
        float my = 1.f - ly, mx = 1.f - lx;
        rwh[sl][0] = h2{(_Float16)(my * mx), (_Float16)(my * mx)};
        rwh[sl][1] = h2{(_Float16)(my * lx), (_Float16)(my * lx)};
        rwh[sl][2] = h2{(_Float16)(ly * mx), (_Float16)(ly * mx)};
        rwh[sl][3] = h2{(_Float16)(ly * lx), (_Float16)(ly * lx)};
        int y0 = (int)y0f, x0 = (int)x0f;
        int lr = y0 + 2 - R0;                // window row of corner A
        int inw = ((unsigned)lr <= 11u);     // rows lr, lr+1 must be in [0,12]
        int lrc = inw ? lr : 0;
        int xx = x0 + 2;                     // always in [0,66]
        int a0 = lrc * RSTR + xsw(xx, chh);
        int a1 = lrc * RSTR + xsw(xx + 1, chh);
        RA[sl] = *(const uint4*)((const char*)xwin + a0);
        RB[sl] = *(const uint4*)((const char*)xwin + a1);
        RC[sl] = *(const uint4*)((const char*)xwin + a0 + RSTR);
        RD[sl] = *(const uint4*)((const char*)xwin + a1 + RSTR);
        rinw[sl] = inw;
        rgy[sl] = y0 + 2;
        rgx[sl] = xx;
    };
    auto consume = [&](int u) {
        int kp = u >> 2, s = u & 3, sl = u & 1;
        if (!__all(rinw[sl])) {              // essentially never taken
            if (!rinw[sl]) {
                int R = rgy[sl], C = rgx[sl];
                RA[sl] = gather_x(R, C);
                RB[sl] = gather_x(R, C + 1);
                RC[sl] = gather_x(R + 1, C);
                RD[sl] = gather_x(R + 1, C + 1);
            }
        }
        const h2* A2 = (const h2*)&RA[sl];
        const h2* B2 = (const h2*)&RB[sl];
        const h2* C2 = (const h2*)&RC[sl];
        const h2* D2 = (const h2*)&RD[sl];
        h2 w0 = rwh[sl][0], w1 = rwh[sl][1], w2 = rwh[sl][2], w3 = rwh[sl][3];
        uint4 afu;
        unsigned* au = (unsigned*)&afu;
        #pragma unroll
        for (int j = 0; j < 4; j++) {
            // fp-contract folds this into 1 pk_mul + 3 v_pk_fma_f16
            h2 v = w0 * A2[j] + w1 * B2[j] + w2 * C2[j] + w3 * D2[j];
            __builtin_memcpy(&au[j], &v, 4);
        }
        f16x8 af = *(f16x8*)&afu;
        acc[s] = __builtin_amdgcn_mfma_f32_16x16x32_f16(af, bwr[kp], acc[s], 0, 0, 0);
    };

    stage(0);
    #pragma unroll
    for (int u = 0; u < 20; u++) {
        if (u < 19) stage(u + 1);
        __builtin_amdgcn_sched_barrier(0);
        consume(u);
    }

    // ---- epilogue: stage f16 results in LDS (group region cc*4224; row
    // stride 264 shorts = 528B, 528%128=16 spreads banks), then coalesced
    // full-line stores. Barrier covers both groups (reads of off_lds done).
    __syncthreads();
    #pragma unroll
    for (int s = 0; s < 4; s++) {
        int colb = (lv * 4 + s) * 16 + q * 4;
        uint2 pk;
        pk.x = hpack(acc[s][0], acc[s][1]);
        pk.y = hpack(acc[s][2], acc[s][3]);
        *(uint2*)(off_lds + cc * 4224 + nn * 264 + colb) = pk;
    }
    __syncthreads();
    {
        int tl = t & 255;                        // local tid within group
        unsigned short* opb = outpre + (size_t)(n * 64 + g * 16) * HW
                            + (chunk2 * 2 + cc) * 256;
        #pragma unroll
        for (int p = 0; p < 2; p++) {
            int idx = p * 256 + tl;
            int ch = idx >> 5, slot = idx & 31;  // 16 ch x 32 slots of 16B
            uint4 vv = *(const uint4*)(off_lds + cc * 4224 + ch * 264 + slot * 8);
            *(uint4*)(opb + (size_t)ch * HW + slot * 8) = vv;
        }
    }
}

// ---------------------------------------------------------------------------
// Kernel C: per-(n,cout) mean/var (single pass) + sigmoid-form tanh GELU.
// Reads f16 outpre (half traffic); n->XCD mapping matches fused_conv
// (fused XCD k owns n in [4k,4k+4) — so does this) for L2 hits.
// ---------------------------------------------------------------------------
__global__ __launch_bounds__(256) void norm_gelu(const unsigned short* __restrict__ outpre,
                                                 float* __restrict__ out)
{
    __shared__ float red[8];
    int bhw = blockIdx.x;
    int bx = (bhw & 7) * 256 + (bhw >> 3);       // same n->XCD map as fused_conv
    int n  = bx >> 6;
    int co = bx & 63;
    int t  = threadIdx.x;

    const uint2* base = (const uint2*)(outpre + (size_t)(n * 64 + co) * HW);
    float4 v[4];
    float s = 0.f, sq = 0.f;
    #pragma unroll
    for (int r = 0; r < 4; r++) {
        uint2 u2 = base[t + r * 256];
        h2 p0, p1;
        __builtin_memcpy(&p0, &u2.x, 4);
        __builtin_memcpy(&p1, &u2.y, 4);
        v[r].x = (float)p0[0]; v[r].y = (float)p0[1];
        v[r].z = (float)p1[0]; v[r].w = (float)p1[1];
        s  += v[r].x + v[r].y + v[r].z + v[r].w;
        sq  = fmaf(v[r].x, v[r].x, sq);
        sq  = fmaf(v[r].y, v[r].y, sq);
        sq  = fmaf(v[r].z, v[r].z, sq);
        sq  = fmaf(v[r].w, v[r].w, sq);
    }
    #pragma unroll
    for (int o2 = 32; o2 > 0; o2 >>= 1) {
        s  += __shfl_down(s,  o2, 64);
        sq += __shfl_down(sq, o2, 64);
    }
    int wid = t >> 6, lane = t & 63;
    if (lane == 0) { red[wid] = s; red[4 + wid] = sq; }
    __syncthreads();
    float S  = red[0] + red[1] + red[2] + red[3];
    float SQ = red[4] + red[5] + red[6] + red[7];
    float mean = S * (1.f / 4096.f);
    float var  = SQ * (1.f / 4096.f) - mean * mean;
    float rstd = rsqrtf(var + 1e-5f);

    int b = n >> 3, d = n & 7;
    float4* outp = (float4*)(out + ((size_t)(b * 64 + co) * 8 + d) * HW);
    #pragma unroll
    for (int r = 0; r < 4; r++) {
        float xs[4] = {v[r].x, v[r].y, v[r].z, v[r].w};
        float4 res;
        float* rp = (float*)&res;
        #pragma unroll
        for (int qq = 0; qq < 4; qq++) {
            float xn = (xs[qq] - mean) * rstd;
            float u = xn * (1.5957691f + 0.0713548162f * xn * xn);
            float e = __expf(-u);
            rp[qq] = xn * __frcp_rn(1.f + e);
        }
        outp[t + r * 256] = res;
    }
}

// ---------------------------------------------------------------------------
extern "C" void kernel_launch(void* const* d_in, const int* in_sizes, int n_in,
                              void* d_out, int out_size, void* d_ws, size_t ws_size,
                              hipStream_t stream) {
    const float* x     = (const float*)d_in[0];
    const float* w_off = (const float*)d_in[1];
    const float* w_dc  = (const float*)d_in[3];
    float* out = (float*)d_out;

    unsigned short* wperm = (unsigned short*)d_ws;                        // 61,440 B
    unsigned short* outpre = (unsigned short*)((char*)d_ws + 61440);      // 16.78 MB f16

    wperm_build<<<120, 256, 0, stream>>>(w_off, w_dc, wperm);
    fused_conv <<<1024, 512, 0, stream>>>(x, wperm,
                                          (const float*)d_in[2],
                                          (const float*)d_in[4], outpre);
    norm_gelu  <<<2048, 256, 0, stream>>>(outpre, out);
}

// Round 10
// 122.845 us; speedup vs baseline: 1.5481x; 1.5481x over previous
//
#include <hip/hip_runtime.h>
#include <hip/hip_fp16.h>
#include <math.h>

#define HW 4096
#define NN 32
#define W68 68
#define RSTR 2192   // window row stride in bytes; 2192 % 128 == 16 so row
                    // jitter rotates the LDS bank group (2176 was 17*128 -> 32-way)

typedef __attribute__((ext_vector_type(8))) _Float16 f16x8;
typedef __attribute__((ext_vector_type(2))) _Float16 h2;
typedef __attribute__((ext_vector_type(4))) float f32x4;

// f32 -> f16 bits, RNE (single v_cvt_f16_f32)
__device__ inline unsigned short hbits(float a) {
    _Float16 h = (_Float16)a;
    unsigned short u;
    __builtin_memcpy(&u, &h, 2);
    return u;
}
// packed f32x2 -> f16x2, RTZ, one v_cvt_pkrtz_f16_f32
__device__ inline unsigned hpack(float a, float b) {
    auto p = __builtin_amdgcn_cvt_pkrtz(a, b);
    unsigned u;
    __builtin_memcpy(&u, &p, 4);
    return u;
}

// swizzled byte offset within one window row: slot = 16 bytes of 8 channels
// (c8 half) at column x. XOR of bit4 with x-bit2 spreads the 32B-stride
// column walk across bank groups.
__device__ inline int xsw(int x, int c8) {
    return ((x << 5) | (c8 << 4)) ^ (((x >> 2) & 1) << 4);
}

// ---------------------------------------------------------------------------
// Kernel W: build the B-fragment-permuted weight buffer wperm (f16).
//   wperm[g*7680 + which*2560 + ((kp*4+q)*16+nn)*8 + j],
//   which: 0=w_dc, 1=w_off rows 0..15, 2=w_off rows 16..17,
//   k=q*8+j -> c=k&15, tap=kp*2+(k>>4); zero for tap>=9.
// ---------------------------------------------------------------------------
__global__ __launch_bounds__(256) void wperm_build(const float* __restrict__ w_off,
                                                   const float* __restrict__ w_dc,
                                                   unsigned short* __restrict__ wperm)
{
    int idx = blockIdx.x * 256 + threadIdx.x;    // < 30720
    int g = idx / 7680;
    int r3 = idx - g * 7680;
    int which = r3 / 2560;
    int r = r3 - which * 2560;
    int j = r & 7;
    int rest = r >> 3;
    int nn_ = rest & 15; rest >>= 4;
    int q_ = rest & 3, kp_ = rest >> 2;
    int k = q_ * 8 + j;
    int c = k & 15, tt = kp_ * 2 + (k >> 4);
    float v = 0.f;
    if (tt < 9) {
        if (which == 0)      v = w_dc[(g * 16 + nn_) * 144 + c * 9 + tt];
        else if (which == 1) v = w_off[(g * 18 + nn_) * 144 + c * 9 + tt];
        else if (nn_ < 2)    v = w_off[(g * 18 + 16 + nn_) * 144 + c * 9 + tt];
    }
    wperm[idx] = hbits(v);
}

// ---------------------------------------------------------------------------
// Kernel F: fused offset-conv + deformable conv, all-f16 datapath.
// 512-THREAD BLOCKS, two independent wave-groups (cc = wv>>2) sharing one
// 13-row f16 x-window (rows R0-2..R0+10, XOR-swizzled, 28.5KB). Group cc
// processes chunk chunk2*2+cc with per-wave code IDENTICAL to the R7 kernel.
// __launch_bounds__(512,4): VGPR cap 128 — SAME cap R7 compiled under (64
// used, no spills). R9's (512,6) capped at 85 and spilled (VGPR 40, WRITE
// 201MB); R8's chunk-loop stretched weight-fragment liveness and spilled.
// LDS = 49.2KB -> 3 blocks/CU x 8 waves = 24 waves/CU (R7: 20), zero tail.
// Bilinear as packed v_pk_fma_f16; MFMA 16x16x32_f16; LDS-staged coalesced
// f16 epilogue. Rare out-of-window lanes fall back to exact fp32-x gathers
// converted with the same cvt_pkrtz (bit-identical).
// ---------------------------------------------------------------------------
__global__ __launch_bounds__(512, 4) void fused_conv(const float* __restrict__ x,
                                                     const unsigned short* __restrict__ wperm,
                                                     const float* __restrict__ b_off,
                                                     const float* __restrict__ b_dc,
                                                     unsigned short* __restrict__ outpre)
{
    __shared__ __attribute__((aligned(16))) unsigned short xwin[14248];        // 13*2192 B
    __shared__ __attribute__((aligned(16))) unsigned short off_lds[2 * 5120];  // 2 x (256x20); also epi buf

    int bhw = blockIdx.x;
    int bx = (bhw & 7) * 128 + (bhw >> 3);       // XCD swizzle (1024%8==0, bijective)
    int n = bx >> 5, g = (bx >> 3) & 3, chunk2 = bx & 7;
    int t = threadIdx.x;
    int lane = t & 63, wv = t >> 6;              // wv in [0,8)
    int cc = wv >> 2, lv = wv & 3;               // wave-group (chunk) / local wave
    int nn = lane & 15, q = lane >> 4;
    int t2 = q >> 1, chh = q & 1;
    int R0 = chunk2 * 8;                         // h of block's first output row

    const unsigned short* wpg = wperm + g * 7680;
    const float* xgbase = x + (size_t)(n * 64 + g * 16) * HW;
    unsigned short* offp = off_lds + cc * 5120;  // this group's offset rows

    // ---- build 13-row window from x: wave w builds rows w and w+8 (w<5).
    {
        int col = lane;                          // x-slot = col+2
        #pragma unroll
        for (int rr = 0; rr < 2; rr++) {
            int r = wv + rr * 8;
            if (r < 13) {                        // wave-uniform
                int h = R0 + r - 2;
                uint4 lo = {0, 0, 0, 0}, hi = {0, 0, 0, 0};
                if ((unsigned)h < 64u) {         // wave-uniform branch
                    const float* xp = xgbase + h * 64 + col;
                    float v[16];
                    #pragma unroll
                    for (int c = 0; c < 16; c++) v[c] = xp[(size_t)c * HW];
                    lo.x = hpack(v[0], v[1]);  lo.y = hpack(v[2], v[3]);
                    lo.z = hpack(v[4], v[5]);  lo.w = hpack(v[6], v[7]);
                    hi.x = hpack(v[8], v[9]);  hi.y = hpack(v[10], v[11]);
                    hi.z = hpack(v[12], v[13]); hi.w = hpack(v[14], v[15]);
                }
                *(uint4*)((char*)xwin + r * RSTR + xsw(col + 2, 0)) = lo;
                *(uint4*)((char*)xwin + r * RSTR + xsw(col + 2, 1)) = hi;
            }
        }
        if (t < 104) {                           // w-halo: cols {0,1,66,67} x 13 rows x 2 c8
            int r = t >> 3, rem = t & 7;
            int xc = rem >> 1, c8 = rem & 1;
            int xx = xc < 2 ? xc : xc + 64;
            uint4 z = {0, 0, 0, 0};
            *(uint4*)((char*)xwin + r * RSTR + xsw(xx, c8)) = z;
        }
    }

    // per-s constants (R7-identical, lv in place of wv)
    int pls[4], xbs[4]; float fx_[4];
    #pragma unroll
    for (int s = 0; s < 4; s++) {
        int pl = (lv * 4 + s) * 16 + nn;
        pls[s] = pl;
        int w = ((lv * 4 + s) & 3) * 16 + nn;
        fx_[s] = (float)(w - 1);
        xbs[s] = w + 1;                          // window col of w
    }
    int rwbase = 4 * cc + lv + 1;                // window row of (h-1)
    float fybase = (float)(R0 + 4 * cc + lv - 1);

    __syncthreads();

    // ================= Phase 1: offset conv (window reads) =================
    {
        f16x8 pb0[5], pb1[5];                    // scoped: dead after phase 1
        #pragma unroll
        for (int kp = 0; kp < 5; kp++) {
            int fo = ((kp * 4 + q) * 16 + nn) * 8;
            pb0[kp] = *(const f16x8*)(wpg + 2560 + fo);
            pb1[kp] = *(const f16x8*)(wpg + 5120 + fo);
        }

        f32x4 acc0[4], acc1[4];
        float bv0 = b_off[g * 18 + nn];
        float bv1 = (nn < 2) ? b_off[g * 18 + 16 + nn] : 0.f;
        #pragma unroll
        for (int s = 0; s < 4; s++)
            #pragma unroll
            for (int r = 0; r < 4; r++) { acc0[s][r] = bv0; acc1[s][r] = bv1; }

        uint4 xv[2][4];
        auto stage1 = [&](int kp) {
            int ki = t2 ? (2 * kp + 1) / 3 : (2 * kp) / 3;
            int kj = t2 ? (2 * kp + 1) % 3 : (2 * kp) % 3;
            int sl = kp & 1;
            #pragma unroll
            for (int s = 0; s < 4; s++) {
                int adr = (rwbase + ki) * RSTR + xsw(xbs[s] + kj, chh);
                xv[sl][s] = *(const uint4*)((const char*)xwin + adr);
            }
        };
        stage1(0);
        #pragma unroll
        for (int kp = 0; kp < 5; kp++) {
            if (kp < 4) stage1(kp + 1);
            __builtin_amdgcn_sched_barrier(0);
            int sl = kp & 1;
            #pragma unroll
            for (int s = 0; s < 4; s++) {
                f16x8 af = *(f16x8*)&xv[sl][s];
                acc0[s] = __builtin_amdgcn_mfma_f32_16x16x32_f16(af, pb0[kp], acc0[s], 0, 0, 0);
                acc1[s] = __builtin_amdgcn_mfma_f32_16x16x32_f16(af, pb1[kp], acc1[s], 0, 0, 0);
            }
        }

        #pragma unroll
        for (int s = 0; s < 4; s++) {
            int pl = (lv * 4 + s) * 16 + q * 4;
            #pragma unroll
            for (int r = 0; r < 4; r++) {
                offp[(pl + r) * 20 + nn] = hbits(acc0[s][r]);
                if (nn < 2)
                    offp[(pl + r) * 20 + 16 + nn] = hbits(acc1[s][r]);
            }
        }
        // zero the 2-short row pad (t in [0,512) covers both groups' rows):
        // tap==9 then reads dy=dx=0 (safe in-window addresses) and its
        // wperm B-slots are zero -> exact 0.
        off_lds[t * 20 + 18] = 0;
        off_lds[t * 20 + 19] = 0;
    }

    // phase-2 B-fragments: issue before the barrier, latency hides under it
    f16x8 bwr[5];
    #pragma unroll
    for (int kp = 0; kp < 5; kp++)
        bwr[kp] = *(const f16x8*)(wpg + ((kp * 4 + q) * 16 + nn) * 8);

    __syncthreads();

    // ================= Phase 2: deformable conv (window reads) =============
    f32x4 acc[4];
    float bvd = b_dc[g * 16 + nn];
    #pragma unroll
    for (int s = 0; s < 4; s++)
        #pragma unroll
        for (int r = 0; r < 4; r++) acc[s][r] = bvd;

    uint4 RA[2], RB[2], RC[2], RD[2];
    h2 rwh[2][4];
    int rinw[2], rgy[2], rgx[2];

    // exact fp32-x fallback gather for out-of-window corners (never taken in
    // practice; same cvt_pkrtz as the window build -> bit-identical)
    auto gather_x = [&](int R, int C) -> uint4 {
        uint4 out = {0, 0, 0, 0};
        int h = R - 2, w = C - 2;
        if ((unsigned)h < 64u && (unsigned)w < 64u) {
            const float* xp = xgbase + (size_t)(chh * 8) * HW + h * 64 + w;
            unsigned* o = (unsigned*)&out;
            #pragma unroll
            for (int k = 0; k < 4; k++)
                o[k] = hpack(xp[(size_t)(2 * k) * HW], xp[(size_t)(2 * k + 1) * HW]);
        }
        return out;
    };

    auto stage = [&](int u) {
        int kp = u >> 2, s = u & 3, sl = u & 1;
        int ki = t2 ? (2 * kp + 1) / 3 : (2 * kp) / 3;
        int kj = t2 ? (2 * kp + 1) % 3 : (2 * kp) % 3;
        unsigned uo = *(const unsigned*)&offp[pls[s] * 20 + 4 * kp + 2 * t2];
        h2 oo;
        __builtin_memcpy(&oo, &uo, 4);
        float py = fybase + (float)ki + (float)oo[0];
        float px = fx_[s] + (float)kj + (float)oo[1];
        float y0f = fminf(fmaxf(floorf(py), -2.f), 64.f);
        float x0f = fminf(fmaxf(floorf(px), -2.f), 64.f);
        float ly = py - y0f, lx = px - x0f;
        float my = 1.f - ly, mx = 1.f - lx;
        rwh[sl][0] = h2{(_Float16)(my * mx), (_Float16)(my * mx)};
        rwh[sl][1] = h2{(_Float16)(my * lx), (_Float16)(my * lx)};
        rwh[sl][2] = h2{(_Float16)(ly * mx), (_Float16)(ly * mx)};
        rwh[sl][3] = h2{(_Float16)(ly * lx), (_Float16)(ly * lx)};
        int y0 = (int)y0f, x0 = (int)x0f;
        int lr = y0 + 2 - R0;                // window row of corner A
        int inw = ((unsigned)lr <= 11u);     // rows lr, lr+1 must be in [0,12]
        int lrc = inw ? lr : 0;
        int xx = x0 + 2;                     // always in [0,66]
        int a0 = lrc * RSTR + xsw(xx, chh);
        int a1 = lrc * RSTR + xsw(xx + 1, chh);
        RA[sl] = *(const uint4*)((const char*)xwin + a0);
        RB[sl] = *(const uint4*)((const char*)xwin + a1);
        RC[sl] = *(const uint4*)((const char*)xwin + a0 + RSTR);
        RD[sl] = *(const uint4*)((const char*)xwin + a1 + RSTR);
        rinw[sl] = inw;
        rgy[sl] = y0 + 2;
        rgx[sl] = xx;
    };
    auto consume = [&](int u) {
        int kp = u >> 2, s = u & 3, sl = u & 1;
        if (!__all(rinw[sl])) {              // essentially never taken
            if (!rinw[sl]) {
                int R = rgy[sl], C = rgx[sl];
                RA[sl] = gather_x(R, C);
                RB[sl] = gather_x(R, C + 1);
                RC[sl] = gather_x(R + 1, C);
                RD[sl] = gather_x(R + 1, C + 1);
            }
        }
        const h2* A2 = (const h2*)&RA[sl];
        const h2* B2 = (const h2*)&RB[sl];
        const h2* C2 = (const h2*)&RC[sl];
        const h2* D2 = (const h2*)&RD[sl];
        h2 w0 = rwh[sl][0], w1 = rwh[sl][1], w2 = rwh[sl][2], w3 = rwh[sl][3];
        uint4 afu;
        unsigned* au = (unsigned*)&afu;
        #pragma unroll
        for (int j = 0; j < 4; j++) {
            // fp-contract folds this into 1 pk_mul + 3 v_pk_fma_f16
            h2 v = w0 * A2[j] + w1 * B2[j] + w2 * C2[j] + w3 * D2[j];
            __builtin_memcpy(&au[j], &v, 4);
        }
        f16x8 af = *(f16x8*)&afu;
        acc[s] = __builtin_amdgcn_mfma_f32_16x16x32_f16(af, bwr[kp], acc[s], 0, 0, 0);
    };

    stage(0);
    #pragma unroll
    for (int u = 0; u < 20; u++) {
        if (u < 19) stage(u + 1);
        __builtin_amdgcn_sched_barrier(0);
        consume(u);
    }

    // ---- epilogue: stage f16 results in LDS (group region cc*4224; row
    // stride 264 shorts = 528B, 528%128=16 spreads banks), then coalesced
    // full-line stores. Barrier covers both groups (reads of off_lds done).
    __syncthreads();
    #pragma unroll
    for (int s = 0; s < 4; s++) {
        int colb = (lv * 4 + s) * 16 + q * 4;
        uint2 pk;
        pk.x = hpack(acc[s][0], acc[s][1]);
        pk.y = hpack(acc[s][2], acc[s][3]);
        *(uint2*)(off_lds + cc * 4224 + nn * 264 + colb) = pk;
    }
    __syncthreads();
    {
        int tl = t & 255;                        // local tid within group
        unsigned short* opb = outpre + (size_t)(n * 64 + g * 16) * HW
                            + (chunk2 * 2 + cc) * 256;
        #pragma unroll
        for (int p = 0; p < 2; p++) {
            int idx = p * 256 + tl;
            int ch = idx >> 5, slot = idx & 31;  // 16 ch x 32 slots of 16B
            uint4 vv = *(const uint4*)(off_lds + cc * 4224 + ch * 264 + slot * 8);
            *(uint4*)(opb + (size_t)ch * HW + slot * 8) = vv;
        }
    }
}

// ---------------------------------------------------------------------------
// Kernel C: per-(n,cout) mean/var (single pass) + sigmoid-form tanh GELU.
// Reads f16 outpre (half traffic); n->XCD mapping matches fused_conv
// (fused XCD k owns n in [4k,4k+4) — so does this) for L2 hits.
// ---------------------------------------------------------------------------
__global__ __launch_bounds__(256) void norm_gelu(const unsigned short* __restrict__ outpre,
                                                 float* __restrict__ out)
{
    __shared__ float red[8];
    int bhw = blockIdx.x;
    int bx = (bhw & 7) * 256 + (bhw >> 3);       // same n->XCD map as fused_conv
    int n  = bx >> 6;
    int co = bx & 63;
    int t  = threadIdx.x;

    const uint2* base = (const uint2*)(outpre + (size_t)(n * 64 + co) * HW);
    float4 v[4];
    float s = 0.f, sq = 0.f;
    #pragma unroll
    for (int r = 0; r < 4; r++) {
        uint2 u2 = base[t + r * 256];
        h2 p0, p1;
        __builtin_memcpy(&p0, &u2.x, 4);
        __builtin_memcpy(&p1, &u2.y, 4);
        v[r].x = (float)p0[0]; v[r].y = (float)p0[1];
        v[r].z = (float)p1[0]; v[r].w = (float)p1[1];
        s  += v[r].x + v[r].y + v[r].z + v[r].w;
        sq  = fmaf(v[r].x, v[r].x, sq);
        sq  = fmaf(v[r].y, v[r].y, sq);
        sq  = fmaf(v[r].z, v[r].z, sq);
        sq  = fmaf(v[r].w, v[r].w, sq);
    }
    #pragma unroll
    for (int o2 = 32; o2 > 0; o2 >>= 1) {
        s  += __shfl_down(s,  o2, 64);
        sq += __shfl_down(sq, o2, 64);
    }
    int wid = t >> 6, lane = t & 63;
    if (lane == 0) { red[wid] = s; red[4 + wid] = sq; }
    __syncthreads();
    float S  = red[0] + red[1] + red[2] + red[3];
    float SQ = red[4] + red[5] + red[6] + red[7];
    float mean = S * (1.f / 4096.f);
    float var  = SQ * (1.f / 4096.f) - mean * mean;
    float rstd = rsqrtf(var + 1e-5f);

    int b = n >> 3, d = n & 7;
    float4* outp = (float4*)(out + ((size_t)(b * 64 + co) * 8 + d) * HW);
    #pragma unroll
    for (int r = 0; r < 4; r++) {
        float xs[4] = {v[r].x, v[r].y, v[r].z, v[r].w};
        float4 res;
        float* rp = (float*)&res;
        #pragma unroll
        for (int qq = 0; qq < 4; qq++) {
            float xn = (xs[qq] - mean) * rstd;
            float u = xn * (1.5957691f + 0.0713548162f * xn * xn);
            float e = __expf(-u);
            rp[qq] = xn * __frcp_rn(1.f + e);
        }
        outp[t + r * 256] = res;
    }
}

// ---------------------------------------------------------------------------
extern "C" void kernel_launch(void* const* d_in, const int* in_sizes, int n_in,
                              void* d_out, int out_size, void* d_ws, size_t ws_size,
                              hipStream_t stream) {
    const float* x     = (const float*)d_in[0];
    const float* w_off = (const float*)d_in[1];
    const float* w_dc  = (const float*)d_in[3];
    float* out = (float*)d_out;

    unsigned short* wperm = (unsigned short*)d_ws;                        // 61,440 B
    unsigned short* outpre = (unsigned short*)((char*)d_ws + 61440);      // 16.78 MB f16

    wperm_build<<<120, 256, 0, stream>>>(w_off, w_dc, wperm);
    fused_conv <<<1024, 512, 0, stream>>>(x, wperm,
                                          (const float*)d_in[2],
                                          (const float*)d_in[4], outpre);
    norm_gelu  <<<2048, 256, 0, stream>>>(outpre, out);
}

// Round 11
// 122.346 us; speedup vs baseline: 1.5544x; 1.0041x over previous
//
#include <hip/hip_runtime.h>
#include <hip/hip_fp16.h>
#include <math.h>

#define HW 4096
#define NN 32
#define W68 68
#define RSTR 2192   // window row stride in bytes; 2192 % 128 == 16 so row
                    // jitter rotates the LDS bank group

typedef __attribute__((ext_vector_type(8))) _Float16 f16x8;
typedef __attribute__((ext_vector_type(2))) _Float16 h2;
typedef __attribute__((ext_vector_type(4))) float f32x4;

// f32 -> f16 bits, RNE (single v_cvt_f16_f32)
__device__ inline unsigned short hbits(float a) {
    _Float16 h = (_Float16)a;
    unsigned short u;
    __builtin_memcpy(&u, &h, 2);
    return u;
}
// packed f32x2 -> f16x2, RTZ, one v_cvt_pkrtz_f16_f32
__device__ inline unsigned hpack(float a, float b) {
    auto p = __builtin_amdgcn_cvt_pkrtz(a, b);
    unsigned u;
    __builtin_memcpy(&u, &p, 4);
    return u;
}

// swizzled byte offset within one window row: slot = 16 bytes of 8 channels
// (c8 half) at column x. XOR of bit4 with x-bit2 spreads the 32B-stride
// column walk across bank groups.
__device__ inline int xsw(int x, int c8) {
    return ((x << 5) | (c8 << 4)) ^ (((x >> 2) & 1) << 4);
}

// ---------------------------------------------------------------------------
// Kernel W: build the B-fragment-permuted weight buffer wperm (f16).
//   wperm[g*7680 + which*2560 + ((kp*4+q)*16+nn)*8 + j],
//   which: 0=w_dc, 1=w_off rows 0..15, 2=w_off rows 16..17,
//   k=q*8+j -> c=k&15, tap=kp*2+(k>>4); zero for tap>=9.
// ---------------------------------------------------------------------------
__global__ __launch_bounds__(256) void wperm_build(const float* __restrict__ w_off,
                                                   const float* __restrict__ w_dc,
                                                   unsigned short* __restrict__ wperm)
{
    int idx = blockIdx.x * 256 + threadIdx.x;    // < 30720
    int g = idx / 7680;
    int r3 = idx - g * 7680;
    int which = r3 / 2560;
    int r = r3 - which * 2560;
    int j = r & 7;
    int rest = r >> 3;
    int nn_ = rest & 15; rest >>= 4;
    int q_ = rest & 3, kp_ = rest >> 2;
    int k = q_ * 8 + j;
    int c = k & 15, tt = kp_ * 2 + (k >> 4);
    float v = 0.f;
    if (tt < 9) {
        if (which == 0)      v = w_dc[(g * 16 + nn_) * 144 + c * 9 + tt];
        else if (which == 1) v = w_off[(g * 18 + nn_) * 144 + c * 9 + tt];
        else if (nn_ < 2)    v = w_off[(g * 18 + 16 + nn_) * 144 + c * 9 + tt];
    }
    wperm[idx] = hbits(v);
}

// ---------------------------------------------------------------------------
// Kernel F: fused offset-conv + deformable conv, all-f16 datapath.
// 512 THREADS / ONE 256-pos CHUNK: 8 waves x 2 s-rows each. 8-row f16
// x-window (rows R0-2..R0+5, XOR-swizzled, 17.5KB) + 18-short off rows
// (9.2KB) = 26.75KB LDS -> thread-limited 4 blocks/CU = 32 waves/CU (max),
// grid 2048 = 8 work/CU = two full dispatch waves, ZERO tail.
// Tap 9 (zero B-slots) aliases tap 8's geometry AND offsets -> always
// in-window, no pad row, no 9th window row. Bilinear as packed v_pk_fma_f16;
// MFMA 16x16x32_f16; LDS-staged coalesced f16 epilogue. Rare out-of-window
// lanes (|off|>~1) fall back to exact fp32-x gathers converted with the same
// cvt_pkrtz (bit-identical).
// ---------------------------------------------------------------------------
__global__ __launch_bounds__(512, 4) void fused_conv(const float* __restrict__ x,
                                                     const unsigned short* __restrict__ wperm,
                                                     const float* __restrict__ b_off,
                                                     const float* __restrict__ b_dc,
                                                     unsigned short* __restrict__ outpre)
{
    __shared__ __attribute__((aligned(16))) unsigned short xwin[8768];        // 8*2192 B
    __shared__ __attribute__((aligned(16))) unsigned short off_lds[4608];     // 256 x 18; also epi buf

    int bhw = blockIdx.x;
    int bx = (bhw & 7) * 256 + (bhw >> 3);       // XCD swizzle (2048%8==0, bijective)
    int n = bx >> 6, g = (bx >> 4) & 3, chunk = bx & 15;
    int t = threadIdx.x;
    int lane = t & 63, lv = t >> 6;              // lv in [0,8): wave id
    int nn = lane & 15, q = lane >> 4;
    int t2 = q >> 1, chh = q & 1;
    int R0 = chunk * 4;                          // h of chunk's first output row

    const unsigned short* wpg = wperm + g * 7680;
    const float* xgbase = x + (size_t)(n * 64 + g * 16) * HW;

    // ---- build 8-row window from x: wave lv builds row lv (h = R0+lv-2).
    {
        int col = lane;                          // x-slot = col+2
        int h = R0 + lv - 2;
        uint4 lo = {0, 0, 0, 0}, hi = {0, 0, 0, 0};
        if ((unsigned)h < 64u) {                 // wave-uniform branch
            const float* xp = xgbase + h * 64 + col;
            float v[16];
            #pragma unroll
            for (int c = 0; c < 16; c++) v[c] = xp[(size_t)c * HW];
            lo.x = hpack(v[0], v[1]);  lo.y = hpack(v[2], v[3]);
            lo.z = hpack(v[4], v[5]);  lo.w = hpack(v[6], v[7]);
            hi.x = hpack(v[8], v[9]);  hi.y = hpack(v[10], v[11]);
            hi.z = hpack(v[12], v[13]); hi.w = hpack(v[14], v[15]);
        }
        *(uint4*)((char*)xwin + lv * RSTR + xsw(col + 2, 0)) = lo;
        *(uint4*)((char*)xwin + lv * RSTR + xsw(col + 2, 1)) = hi;

        if (t < 64) {                            // w-halo: cols {0,1,66,67} x 8 rows x 2 c8
            int r = t >> 3, rem = t & 7;
            int xc = rem >> 1, c8 = rem & 1;
            int xx = xc < 2 ? xc : xc + 64;
            uint4 z = {0, 0, 0, 0};
            *(uint4*)((char*)xwin + r * RSTR + xsw(xx, c8)) = z;
        }
    }

    // per-s constants: wave lv owns chunk rows rw = 2lv, 2lv+1
    // h = R0 + (rw>>2) (uniform per wave), w = ((rw&3))*16 + nn
    int pls[2], xbs[2]; float fx_[2];
    #pragma unroll
    for (int s = 0; s < 2; s++) {
        int rw = 2 * lv + s;
        pls[s] = rw * 16 + nn;
        int w = (rw & 3) * 16 + nn;
        fx_[s] = (float)(w - 1);
        xbs[s] = w + 1;                          // window col of w
    }
    int wr1 = (lv >> 1) + 1;                     // window row of (h-1)
    float fybase = (float)(R0 + (lv >> 1) - 1);  // h-1

    __syncthreads();

    // ================= Phase 1: offset conv (window reads) =================
    {
        f16x8 pb0[5], pb1[5];                    // scoped: dead after phase 1
        #pragma unroll
        for (int kp = 0; kp < 5; kp++) {
            int fo = ((kp * 4 + q) * 16 + nn) * 8;
            pb0[kp] = *(const f16x8*)(wpg + 2560 + fo);
            pb1[kp] = *(const f16x8*)(wpg + 5120 + fo);
        }

        f32x4 acc0[2], acc1[2];
        float bv0 = b_off[g * 18 + nn];
        float bv1 = (nn < 2) ? b_off[g * 18 + 16 + nn] : 0.f;
        #pragma unroll
        for (int s = 0; s < 2; s++)
            #pragma unroll
            for (int r = 0; r < 4; r++) { acc0[s][r] = bv0; acc1[s][r] = bv1; }

        uint4 xv[2][2];
        // phase-1 taps: tap = 2kp+t2 (tap 9 reads real row data, B-slots zero;
        // row wr1+3 <= 7 in-window)
        auto stage1 = [&](int kp) {
            int ki = t2 ? (2 * kp + 1) / 3 : (2 * kp) / 3;
            int kj = t2 ? (2 * kp + 1) % 3 : (2 * kp) % 3;
            int sl = kp & 1;
            #pragma unroll
            for (int s = 0; s < 2; s++) {
                int adr = (wr1 + ki) * RSTR + xsw(xbs[s] + kj, chh);
                xv[sl][s] = *(const uint4*)((const char*)xwin + adr);
            }
        };
        stage1(0);
        #pragma unroll
        for (int kp = 0; kp < 5; kp++) {
            if (kp < 4) stage1(kp + 1);
            __builtin_amdgcn_sched_barrier(0);
            int sl = kp & 1;
            #pragma unroll
            for (int s = 0; s < 2; s++) {
                f16x8 af = *(f16x8*)&xv[sl][s];
                acc0[s] = __builtin_amdgcn_mfma_f32_16x16x32_f16(af, pb0[kp], acc0[s], 0, 0, 0);
                acc1[s] = __builtin_amdgcn_mfma_f32_16x16x32_f16(af, pb1[kp], acc1[s], 0, 0, 0);
            }
        }

        #pragma unroll
        for (int s = 0; s < 2; s++) {
            int pl = (2 * lv + s) * 16 + q * 4;
            #pragma unroll
            for (int r = 0; r < 4; r++) {
                off_lds[(pl + r) * 18 + nn] = hbits(acc0[s][r]);
                if (nn < 2)
                    off_lds[(pl + r) * 18 + 16 + nn] = hbits(acc1[s][r]);
            }
        }
    }

    // phase-2 B-fragments: issue before the barrier, latency hides under it
    f16x8 bwr[5];
    #pragma unroll
    for (int kp = 0; kp < 5; kp++)
        bwr[kp] = *(const f16x8*)(wpg + ((kp * 4 + q) * 16 + nn) * 8);

    __syncthreads();

    // ================= Phase 2: deformable conv (window reads) =============
    f32x4 acc[2];
    float bvd = b_dc[g * 16 + nn];
    #pragma unroll
    for (int s = 0; s < 2; s++)
        #pragma unroll
        for (int r = 0; r < 4; r++) acc[s][r] = bvd;

    uint4 RA[2], RB[2], RC[2], RD[2];
    h2 rwh[2][4];
    int rinw[2], rgy[2], rgx[2];

    // exact fp32-x fallback gather for out-of-window corners (never taken in
    // practice; same cvt_pkrtz as the window build -> bit-identical)
    auto gather_x = [&](int R, int C) -> uint4 {
        uint4 out = {0, 0, 0, 0};
        int h = R - 2, w = C - 2;
        if ((unsigned)h < 64u && (unsigned)w < 64u) {
            const float* xp = xgbase + (size_t)(chh * 8) * HW + h * 64 + w;
            unsigned* o = (unsigned*)&out;
            #pragma unroll
            for (int k = 0; k < 4; k++)
                o[k] = hpack(xp[(size_t)(2 * k) * HW], xp[(size_t)(2 * k + 1) * HW]);
        }
        return out;
    };

    // 10 units: kp = u>>1, s = u&1. Tap 9 (kp==4, t2==1) aliases tap 8:
    // same ki,kj AND same offset slot -> in-window; its B-slots are zero.
    auto stage = [&](int u) {
        int kp = u >> 1, s = u & 1, sl = u & 1;
        int ki, kj, toff;
        if (kp == 4) { ki = 2; kj = 2; toff = 16; }
        else {
            ki = t2 ? (2 * kp + 1) / 3 : (2 * kp) / 3;
            kj = t2 ? (2 * kp + 1) % 3 : (2 * kp) % 3;
            toff = 4 * kp + 2 * t2;
        }
        unsigned uo = *(const unsigned*)&off_lds[pls[s] * 18 + toff];
        h2 oo;
        __builtin_memcpy(&oo, &uo, 4);
        float py = fybase + (float)ki + (float)oo[0];
        float px = fx_[s] + (float)kj + (float)oo[1];
        float y0f = fminf(fmaxf(floorf(py), -2.f), 64.f);
        float x0f = fminf(fmaxf(floorf(px), -2.f), 64.f);
        float ly = py - y0f, lx = px - x0f;
        float my = 1.f - ly, mx = 1.f - lx;
        rwh[sl][0] = h2{(_Float16)(my * mx), (_Float16)(my * mx)};
        rwh[sl][1] = h2{(_Float16)(my * lx), (_Float16)(my * lx)};
        rwh[sl][2] = h2{(_Float16)(ly * mx), (_Float16)(ly * mx)};
        rwh[sl][3] = h2{(_Float16)(ly * lx), (_Float16)(ly * lx)};
        int y0 = (int)y0f, x0 = (int)x0f;
        int lr = y0 + 2 - R0;                // window row of corner A
        int inw = ((unsigned)lr <= 6u);      // rows lr, lr+1 must be in [0,7]
        int lrc = inw ? lr : 0;
        int xx = x0 + 2;                     // always in [0,66]
        int a0 = lrc * RSTR + xsw(xx, chh);
        int a1 = lrc * RSTR + xsw(xx + 1, chh);
        RA[sl] = *(const uint4*)((const char*)xwin + a0);
        RB[sl] = *(const uint4*)((const char*)xwin + a1);
        RC[sl] = *(const uint4*)((const char*)xwin + a0 + RSTR);
        RD[sl] = *(const uint4*)((const char*)xwin + a1 + RSTR);
        rinw[sl] = inw;
        rgy[sl] = y0 + 2;
        rgx[sl] = xx;
    };
    auto consume = [&](int u) {
        int kp = u >> 1, s = u & 1, sl = u & 1;
        if (!__all(rinw[sl])) {              // essentially never taken
            if (!rinw[sl]) {
                int R = rgy[sl], C = rgx[sl];
                RA[sl] = gather_x(R, C);
                RB[sl] = gather_x(R, C + 1);
                RC[sl] = gather_x(R + 1, C);
                RD[sl] = gather_x(R + 1, C + 1);
            }
        }
        const h2* A2 = (const h2*)&RA[sl];
        const h2* B2 = (const h2*)&RB[sl];
        const h2* C2 = (const h2*)&RC[sl];
        const h2* D2 = (const h2*)&RD[sl];
        h2 w0 = rwh[sl][0], w1 = rwh[sl][1], w2 = rwh[sl][2], w3 = rwh[sl][3];
        uint4 afu;
        unsigned* au = (unsigned*)&afu;
        #pragma unroll
        for (int j = 0; j < 4; j++) {
            // fp-contract folds this into 1 pk_mul + 3 v_pk_fma_f16
            h2 v = w0 * A2[j] + w1 * B2[j] + w2 * C2[j] + w3 * D2[j];
            __builtin_memcpy(&au[j], &v, 4);
        }
        f16x8 af = *(f16x8*)&afu;
        acc[s] = __builtin_amdgcn_mfma_f32_16x16x32_f16(af, bwr[kp], acc[s], 0, 0, 0);
    };

    stage(0);
    #pragma unroll
    for (int u = 0; u < 10; u++) {
        if (u < 9) stage(u + 1);
        __builtin_amdgcn_sched_barrier(0);
        consume(u);
    }

    // ---- epilogue: stage f16 results in LDS (reuse off_lds; row stride
    // 264 shorts = 528B, 528%128=16 spreads banks), then one coalesced
    // 16B store per thread (16ch x 32 slots = 512).
    __syncthreads();                         // all off_lds/xwin reads done
    #pragma unroll
    for (int s = 0; s < 2; s++) {
        int colb = (2 * lv + s) * 16 + q * 4;
        uint2 pk;
        pk.x = hpack(acc[s][0], acc[s][1]);
        pk.y = hpack(acc[s][2], acc[s][3]);
        *(uint2*)(off_lds + nn * 264 + colb) = pk;
    }
    __syncthreads();
    {
        int ch = t >> 5, slot = t & 31;      // 16 ch x 32 slots of 16B
        unsigned short* opb = outpre + (size_t)(n * 64 + g * 16) * HW + chunk * 256;
        uint4 vv = *(const uint4*)(off_lds + ch * 264 + slot * 8);
        *(uint4*)(opb + (size_t)ch * HW + slot * 8) = vv;
    }
}

// ---------------------------------------------------------------------------
// Kernel C: per-(n,cout) mean/var (single pass) + sigmoid-form tanh GELU.
// Reads f16 outpre (half traffic); n->XCD mapping matches fused_conv
// for L2 hits on the freshly-written outpre.
// ---------------------------------------------------------------------------
__global__ __launch_bounds__(256) void norm_gelu(const unsigned short* __restrict__ outpre,
                                                 float* __restrict__ out)
{
    __shared__ float red[8];
    int bhw = blockIdx.x;
    int bx = (bhw & 7) * 256 + (bhw >> 3);       // same n->XCD map as fused_conv
    int n  = bx >> 6;
    int co = bx & 63;
    int t  = threadIdx.x;

    const uint2* base = (const uint2*)(outpre + (size_t)(n * 64 + co) * HW);
    float4 v[4];
    float s = 0.f, sq = 0.f;
    #pragma unroll
    for (int r = 0; r < 4; r++) {
        uint2 u2 = base[t + r * 256];
        h2 p0, p1;
        __builtin_memcpy(&p0, &u2.x, 4);
        __builtin_memcpy(&p1, &u2.y, 4);
        v[r].x = (float)p0[0]; v[r].y = (float)p0[1];
        v[r].z = (float)p1[0]; v[r].w = (float)p1[1];
        s  += v[r].x + v[r].y + v[r].z + v[r].w;
        sq  = fmaf(v[r].x, v[r].x, sq);
        sq  = fmaf(v[r].y, v[r].y, sq);
        sq  = fmaf(v[r].z, v[r].z, sq);
        sq  = fmaf(v[r].w, v[r].w, sq);
    }
    #pragma unroll
    for (int o2 = 32; o2 > 0; o2 >>= 1) {
        s  += __shfl_down(s,  o2, 64);
        sq += __shfl_down(sq, o2, 64);
    }
    int wid = t >> 6, lane = t & 63;
    if (lane == 0) { red[wid] = s; red[4 + wid] = sq; }
    __syncthreads();
    float S  = red[0] + red[1] + red[2] + red[3];
    float SQ = red[4] + red[5] + red[6] + red[7];
    float mean = S * (1.f / 4096.f);
    float var  = SQ * (1.f / 4096.f) - mean * mean;
    float rstd = rsqrtf(var + 1e-5f);

    int b = n >> 3, d = n & 7;
    float4* outp = (float4*)(out + ((size_t)(b * 64 + co) * 8 + d) * HW);
    #pragma unroll
    for (int r = 0; r < 4; r++) {
        float xs[4] = {v[r].x, v[r].y, v[r].z, v[r].w};
        float4 res;
        float* rp = (float*)&res;
        #pragma unroll
        for (int qq = 0; qq < 4; qq++) {
            float xn = (xs[qq] - mean) * rstd;
            float u = xn * (1.5957691f + 0.0713548162f * xn * xn);
            float e = __expf(-u);
            rp[qq] = xn * __frcp_rn(1.f + e);
        }
        outp[t + r * 256] = res;
    }
}

// ---------------------------------------------------------------------------
extern "C" void kernel_launch(void* const* d_in, const int* in_sizes, int n_in,
                              void* d_out, int out_size, void* d_ws, size_t ws_size,
                              hipStream_t stream) {
    const float* x     = (const float*)d_in[0];
    const float* w_off = (const float*)d_in[1];
    const float* w_dc  = (const float*)d_in[3];
    float* out = (float*)d_out;

    unsigned short* wperm = (unsigned short*)d_ws;                        // 61,440 B
    unsigned short* outpre = (unsigned short*)((char*)d_ws + 61440);      // 16.78 MB f16

    wperm_build<<<120, 256, 0, stream>>>(w_off, w_dc, wperm);
    fused_conv <<<2048, 512, 0, stream>>>(x, wperm,
                                          (const float*)d_in[2],
                                          (const float*)d_in[4], outpre);
    norm_gelu  <<<2048, 256, 0, stream>>>(outpre, out);
}

// Round 12
// 119.592 us; speedup vs baseline: 1.5902x; 1.0230x over previous
//
#include <hip/hip_runtime.h>
#include <hip/hip_fp16.h>
#include <math.h>

#define HW 4096
#define NN 32
#define W68 68
#define RSTR 2192   // window row stride in bytes; 2192 % 128 == 16 so row
                    // jitter rotates the LDS bank group

typedef __attribute__((ext_vector_type(8))) _Float16 f16x8;
typedef __attribute__((ext_vector_type(2))) _Float16 h2;
typedef __attribute__((ext_vector_type(4))) float f32x4;

// f32 -> f16 bits, RNE (single v_cvt_f16_f32)
__device__ inline unsigned short hbits(float a) {
    _Float16 h = (_Float16)a;
    unsigned short u;
    __builtin_memcpy(&u, &h, 2);
    return u;
}
// packed f32x2 -> f16x2, RTZ, one v_cvt_pkrtz_f16_f32
__device__ inline unsigned hpack(float a, float b) {
    auto p = __builtin_amdgcn_cvt_pkrtz(a, b);
    unsigned u;
    __builtin_memcpy(&u, &p, 4);
    return u;
}

// swizzled byte offset within one window row: slot = 16 bytes of 8 channels
// (c8 half) at column x. XOR of bit4 with x-bit2 spreads the 32B-stride
// column walk across bank groups.
__device__ inline int xsw(int x, int c8) {
    return ((x << 5) | (c8 << 4)) ^ (((x >> 2) & 1) << 4);
}

// ---------------------------------------------------------------------------
// Kernel W: build the B-fragment-permuted weight buffer wperm (f16).
//   wperm[g*7680 + which*2560 + ((kp*4+q)*16+nn)*8 + j],
//   which: 0=w_dc, 1=w_off rows 0..15, 2=w_off rows 16..17,
//   k=q*8+j -> c=k&15, tap=kp*2+(k>>4); zero for tap>=9.
// ---------------------------------------------------------------------------
__global__ __launch_bounds__(256) void wperm_build(const float* __restrict__ w_off,
                                                   const float* __restrict__ w_dc,
                                                   unsigned short* __restrict__ wperm)
{
    int idx = blockIdx.x * 256 + threadIdx.x;    // < 30720
    int g = idx / 7680;
    int r3 = idx - g * 7680;
    int which = r3 / 2560;
    int r = r3 - which * 2560;
    int j = r & 7;
    int rest = r >> 3;
    int nn_ = rest & 15; rest >>= 4;
    int q_ = rest & 3, kp_ = rest >> 2;
    int k = q_ * 8 + j;
    int c = k & 15, tt = kp_ * 2 + (k >> 4);
    float v = 0.f;
    if (tt < 9) {
        if (which == 0)      v = w_dc[(g * 16 + nn_) * 144 + c * 9 + tt];
        else if (which == 1) v = w_off[(g * 18 + nn_) * 144 + c * 9 + tt];
        else if (nn_ < 2)    v = w_off[(g * 18 + 16 + nn_) * 144 + c * 9 + tt];
    }
    wperm[idx] = hbits(v);
}

// ---------------------------------------------------------------------------
// Kernel F: fused offset-conv + deformable conv, all-f16 datapath.
// 512 THREADS / ONE 256-pos CHUNK: 8 waves x 2 s-rows each. 8-row f16
// x-window (rows R0-2..R0+5, XOR-swizzled, 17.5KB) + 18-short off rows
// (9.2KB) = 26.75KB LDS -> 4 blocks/CU = 32 waves/CU, grid 2048 = 8/CU,
// zero dispatch tail. NO barrier between phase 1 and phase 2: wave lv's
// off_lds rows (positions (2lv..2lv+1)*16) are written AND read only by
// wave lv — the dependency is wave-internal, ordered by lgkmcnt. Waves
// therefore stream phase1+phase2 back-to-back at staggered times, keeping
// the LDS pipe (the bottleneck: ~50 ds_read_b128/lane) continuously fed
// instead of bursting in lockstep. The epilogue barrier (cross-wave
// off_lds reuse as staging) remains. Tap 9 (zero B-slots) aliases tap 8.
// Bilinear as packed v_pk_fma_f16; MFMA 16x16x32_f16; LDS-staged coalesced
// f16 epilogue. Rare out-of-window lanes fall back to exact fp32-x gathers
// converted with the same cvt_pkrtz (bit-identical).
// ---------------------------------------------------------------------------
__global__ __launch_bounds__(512, 4) void fused_conv(const float* __restrict__ x,
                                                     const unsigned short* __restrict__ wperm,
                                                     const float* __restrict__ b_off,
                                                     const float* __restrict__ b_dc,
                                                     unsigned short* __restrict__ outpre)
{
    __shared__ __attribute__((aligned(16))) unsigned short xwin[8768];        // 8*2192 B
    __shared__ __attribute__((aligned(16))) unsigned short off_lds[4608];     // 256 x 18; also epi buf

    int bhw = blockIdx.x;
    int bx = (bhw & 7) * 256 + (bhw >> 3);       // XCD swizzle (2048%8==0, bijective)
    int n = bx >> 6, g = (bx >> 4) & 3, chunk = bx & 15;
    int t = threadIdx.x;
    int lane = t & 63, lv = t >> 6;              // lv in [0,8): wave id
    int nn = lane & 15, q = lane >> 4;
    int t2 = q >> 1, chh = q & 1;
    int R0 = chunk * 4;                          // h of chunk's first output row

    const unsigned short* wpg = wperm + g * 7680;
    const float* xgbase = x + (size_t)(n * 64 + g * 16) * HW;

    // ---- build 8-row window from x: wave lv builds row lv (h = R0+lv-2).
    {
        int col = lane;                          // x-slot = col+2
        int h = R0 + lv - 2;
        uint4 lo = {0, 0, 0, 0}, hi = {0, 0, 0, 0};
        if ((unsigned)h < 64u) {                 // wave-uniform branch
            const float* xp = xgbase + h * 64 + col;
            float v[16];
            #pragma unroll
            for (int c = 0; c < 16; c++) v[c] = xp[(size_t)c * HW];
            lo.x = hpack(v[0], v[1]);  lo.y = hpack(v[2], v[3]);
            lo.z = hpack(v[4], v[5]);  lo.w = hpack(v[6], v[7]);
            hi.x = hpack(v[8], v[9]);  hi.y = hpack(v[10], v[11]);
            hi.z = hpack(v[12], v[13]); hi.w = hpack(v[14], v[15]);
        }
        *(uint4*)((char*)xwin + lv * RSTR + xsw(col + 2, 0)) = lo;
        *(uint4*)((char*)xwin + lv * RSTR + xsw(col + 2, 1)) = hi;

        if (t < 64) {                            // w-halo: cols {0,1,66,67} x 8 rows x 2 c8
            int r = t >> 3, rem = t & 7;
            int xc = rem >> 1, c8 = rem & 1;
            int xx = xc < 2 ? xc : xc + 64;
            uint4 z = {0, 0, 0, 0};
            *(uint4*)((char*)xwin + r * RSTR + xsw(xx, c8)) = z;
        }
    }

    // per-s constants: wave lv owns chunk rows rw = 2lv, 2lv+1
    int pls[2], xbs[2]; float fx_[2];
    #pragma unroll
    for (int s = 0; s < 2; s++) {
        int rw = 2 * lv + s;
        pls[s] = rw * 16 + nn;
        int w = (rw & 3) * 16 + nn;
        fx_[s] = (float)(w - 1);
        xbs[s] = w + 1;                          // window col of w
    }
    int wr1 = (lv >> 1) + 1;                     // window row of (h-1)
    float fybase = (float)(R0 + (lv >> 1) - 1);  // h-1

    __syncthreads();                             // xwin build complete (cross-wave)

    // ================= Phase 1: offset conv (window reads) =================
    {
        f16x8 pb0[5], pb1[5];                    // scoped: dead after phase 1
        #pragma unroll
        for (int kp = 0; kp < 5; kp++) {
            int fo = ((kp * 4 + q) * 16 + nn) * 8;
            pb0[kp] = *(const f16x8*)(wpg + 2560 + fo);
            pb1[kp] = *(const f16x8*)(wpg + 5120 + fo);
        }

        f32x4 acc0[2], acc1[2];
        float bv0 = b_off[g * 18 + nn];
        float bv1 = (nn < 2) ? b_off[g * 18 + 16 + nn] : 0.f;
        #pragma unroll
        for (int s = 0; s < 2; s++)
            #pragma unroll
            for (int r = 0; r < 4; r++) { acc0[s][r] = bv0; acc1[s][r] = bv1; }

        uint4 xv[2][2];
        auto stage1 = [&](int kp) {
            int ki = t2 ? (2 * kp + 1) / 3 : (2 * kp) / 3;
            int kj = t2 ? (2 * kp + 1) % 3 : (2 * kp) % 3;
            int sl = kp & 1;
            #pragma unroll
            for (int s = 0; s < 2; s++) {
                int adr = (wr1 + ki) * RSTR + xsw(xbs[s] + kj, chh);
                xv[sl][s] = *(const uint4*)((const char*)xwin + adr);
            }
        };
        stage1(0);
        #pragma unroll
        for (int kp = 0; kp < 5; kp++) {
            if (kp < 4) stage1(kp + 1);
            __builtin_amdgcn_sched_barrier(0);
            int sl = kp & 1;
            #pragma unroll
            for (int s = 0; s < 2; s++) {
                f16x8 af = *(f16x8*)&xv[sl][s];
                acc0[s] = __builtin_amdgcn_mfma_f32_16x16x32_f16(af, pb0[kp], acc0[s], 0, 0, 0);
                acc1[s] = __builtin_amdgcn_mfma_f32_16x16x32_f16(af, pb1[kp], acc1[s], 0, 0, 0);
            }
        }

        #pragma unroll
        for (int s = 0; s < 2; s++) {
            int pl = (2 * lv + s) * 16 + q * 4;
            #pragma unroll
            for (int r = 0; r < 4; r++) {
                off_lds[(pl + r) * 18 + nn] = hbits(acc0[s][r]);
                if (nn < 2)
                    off_lds[(pl + r) * 18 + 16 + nn] = hbits(acc1[s][r]);
            }
        }
    }

    // phase-2 B-fragments (global, L2-hot)
    f16x8 bwr[5];
    #pragma unroll
    for (int kp = 0; kp < 5; kp++)
        bwr[kp] = *(const f16x8*)(wpg + ((kp * 4 + q) * 16 + nn) * 8);

    // NO __syncthreads here: wave lv's off_lds rows are wave-private
    // (written above by this wave, read below by this wave); lgkmcnt
    // orders the in-wave LDS write->read. Waves stream ahead staggered.

    // ================= Phase 2: deformable conv (window reads) =============
    f32x4 acc[2];
    float bvd = b_dc[g * 16 + nn];
    #pragma unroll
    for (int s = 0; s < 2; s++)
        #pragma unroll
        for (int r = 0; r < 4; r++) acc[s][r] = bvd;

    uint4 RA[2], RB[2], RC[2], RD[2];
    h2 rwh[2][4];
    int rinw[2], rgy[2], rgx[2];

    // exact fp32-x fallback gather for out-of-window corners (never taken in
    // practice; same cvt_pkrtz as the window build -> bit-identical)
    auto gather_x = [&](int R, int C) -> uint4 {
        uint4 out = {0, 0, 0, 0};
        int h = R - 2, w = C - 2;
        if ((unsigned)h < 64u && (unsigned)w < 64u) {
            const float* xp = xgbase + (size_t)(chh * 8) * HW + h * 64 + w;
            unsigned* o = (unsigned*)&out;
            #pragma unroll
            for (int k = 0; k < 4; k++)
                o[k] = hpack(xp[(size_t)(2 * k) * HW], xp[(size_t)(2 * k + 1) * HW]);
        }
        return out;
    };

    // 10 units: kp = u>>1, s = u&1. Tap 9 (kp==4, t2==1) aliases tap 8:
    // same ki,kj AND same offset slot -> in-window; its B-slots are zero.
    auto stage = [&](int u) {
        int kp = u >> 1, s = u & 1, sl = u & 1;
        int ki, kj, toff;
        if (kp == 4) { ki = 2; kj = 2; toff = 16; }
        else {
            ki = t2 ? (2 * kp + 1) / 3 : (2 * kp) / 3;
            kj = t2 ? (2 * kp + 1) % 3 : (2 * kp) % 3;
            toff = 4 * kp + 2 * t2;
        }
        unsigned uo = *(const unsigned*)&off_lds[pls[s] * 18 + toff];
        h2 oo;
        __builtin_memcpy(&oo, &uo, 4);
        float py = fybase + (float)ki + (float)oo[0];
        float px = fx_[s] + (float)kj + (float)oo[1];
        float y0f = fminf(fmaxf(floorf(py), -2.f), 64.f);
        float x0f = fminf(fmaxf(floorf(px), -2.f), 64.f);
        float ly = py - y0f, lx = px - x0f;
        float my = 1.f - ly, mx = 1.f - lx;
        rwh[sl][0] = h2{(_Float16)(my * mx), (_Float16)(my * mx)};
        rwh[sl][1] = h2{(_Float16)(my * lx), (_Float16)(my * lx)};
        rwh[sl][2] = h2{(_Float16)(ly * mx), (_Float16)(ly * mx)};
        rwh[sl][3] = h2{(_Float16)(ly * lx), (_Float16)(ly * lx)};
        int y0 = (int)y0f, x0 = (int)x0f;
        int lr = y0 + 2 - R0;                // window row of corner A
        int inw = ((unsigned)lr <= 6u);      // rows lr, lr+1 must be in [0,7]
        int lrc = inw ? lr : 0;
        int xx = x0 + 2;                     // always in [0,66]
        int a0 = lrc * RSTR + xsw(xx, chh);
        int a1 = lrc * RSTR + xsw(xx + 1, chh);
        RA[sl] = *(const uint4*)((const char*)xwin + a0);
        RB[sl] = *(const uint4*)((const char*)xwin + a1);
        RC[sl] = *(const uint4*)((const char*)xwin + a0 + RSTR);
        RD[sl] = *(const uint4*)((const char*)xwin + a1 + RSTR);
        rinw[sl] = inw;
        rgy[sl] = y0 + 2;
        rgx[sl] = xx;
    };
    auto consume = [&](int u) {
        int kp = u >> 1, s = u & 1, sl = u & 1;
        if (!__all(rinw[sl])) {              // essentially never taken
            if (!rinw[sl]) {
                int R = rgy[sl], C = rgx[sl];
                RA[sl] = gather_x(R, C);
                RB[sl] = gather_x(R, C + 1);
                RC[sl] = gather_x(R + 1, C);
                RD[sl] = gather_x(R + 1, C + 1);
            }
        }
        const h2* A2 = (const h2*)&RA[sl];
        const h2* B2 = (const h2*)&RB[sl];
        const h2* C2 = (const h2*)&RC[sl];
        const h2* D2 = (const h2*)&RD[sl];
        h2 w0 = rwh[sl][0], w1 = rwh[sl][1], w2 = rwh[sl][2], w3 = rwh[sl][3];
        uint4 afu;
        unsigned* au = (unsigned*)&afu;
        #pragma unroll
        for (int j = 0; j < 4; j++) {
            // fp-contract folds this into 1 pk_mul + 3 v_pk_fma_f16
            h2 v = w0 * A2[j] + w1 * B2[j] + w2 * C2[j] + w3 * D2[j];
            __builtin_memcpy(&au[j], &v, 4);
        }
        f16x8 af = *(f16x8*)&afu;
        acc[s] = __builtin_amdgcn_mfma_f32_16x16x32_f16(af, bwr[kp], acc[s], 0, 0, 0);
    };

    stage(0);
    #pragma unroll
    for (int u = 0; u < 10; u++) {
        if (u < 9) stage(u + 1);
        __builtin_amdgcn_sched_barrier(0);
        consume(u);
    }

    // ---- epilogue: stage f16 results in LDS (reuse off_lds; row stride
    // 264 shorts = 528B, 528%128=16 spreads banks), then one coalesced
    // 16B store per thread (16ch x 32 slots = 512). The barrier is REQUIRED:
    // epi staging rows (nn*264) overlap other waves' off_lds rows.
    __syncthreads();
    #pragma unroll
    for (int s = 0; s < 2; s++) {
        int colb = (2 * lv + s) * 16 + q * 4;
        uint2 pk;
        pk.x = hpack(acc[s][0], acc[s][1]);
        pk.y = hpack(acc[s][2], acc[s][3]);
        *(uint2*)(off_lds + nn * 264 + colb) = pk;
    }
    __syncthreads();
    {
        int ch = t >> 5, slot = t & 31;      // 16 ch x 32 slots of 16B
        unsigned short* opb = outpre + (size_t)(n * 64 + g * 16) * HW + chunk * 256;
        uint4 vv = *(const uint4*)(off_lds + ch * 264 + slot * 8);
        *(uint4*)(opb + (size_t)ch * HW + slot * 8) = vv;
    }
}

// ---------------------------------------------------------------------------
// Kernel C: per-(n,cout) mean/var (single pass) + sigmoid-form tanh GELU.
// Reads f16 outpre (half traffic); n->XCD mapping matches fused_conv
// for L2 hits on the freshly-written outpre.
// ---------------------------------------------------------------------------
__global__ __launch_bounds__(256) void norm_gelu(const unsigned short* __restrict__ outpre,
                                                 float* __restrict__ out)
{
    __shared__ float red[8];
    int bhw = blockIdx.x;
    int bx = (bhw & 7) * 256 + (bhw >> 3);       // same n->XCD map as fused_conv
    int n  = bx >> 6;
    int co = bx & 63;
    int t  = threadIdx.x;

    const uint2* base = (const uint2*)(outpre + (size_t)(n * 64 + co) * HW);
    float4 v[4];
    float s = 0.f, sq = 0.f;
    #pragma unroll
    for (int r = 0; r < 4; r++) {
        uint2 u2 = base[t + r * 256];
        h2 p0, p1;
        __builtin_memcpy(&p0, &u2.x, 4);
        __builtin_memcpy(&p1, &u2.y, 4);
        v[r].x = (float)p0[0]; v[r].y = (float)p0[1];
        v[r].z = (float)p1[0]; v[r].w = (float)p1[1];
        s  += v[r].x + v[r].y + v[r].z + v[r].w;
        sq  = fmaf(v[r].x, v[r].x, sq);
        sq  = fmaf(v[r].y, v[r].y, sq);
        sq  = fmaf(v[r].z, v[r].z, sq);
        sq  = fmaf(v[r].w, v[r].w, sq);
    }
    #pragma unroll
    for (int o2 = 32; o2 > 0; o2 >>= 1) {
        s  += __shfl_down(s,  o2, 64);
        sq += __shfl_down(sq, o2, 64);
    }
    int wid = t >> 6, lane = t & 63;
    if (lane == 0) { red[wid] = s; red[4 + wid] = sq; }
    __syncthreads();
    float S  = red[0] + red[1] + red[2] + red[3];
    float SQ = red[4] + red[5] + red[6] + red[7];
    float mean = S * (1.f / 4096.f);
    float var  = SQ * (1.f / 4096.f) - mean * mean;
    float rstd = rsqrtf(var + 1e-5f);

    int b = n >> 3, d = n & 7;
    float4* outp = (float4*)(out + ((size_t)(b * 64 + co) * 8 + d) * HW);
    #pragma unroll
    for (int r = 0; r < 4; r++) {
        float xs[4] = {v[r].x, v[r].y, v[r].z, v[r].w};
        float4 res;
        float* rp = (float*)&res;
        #pragma unroll
        for (int qq = 0; qq < 4; qq++) {
            float xn = (xs[qq] - mean) * rstd;
            float u = xn * (1.5957691f + 0.0713548162f * xn * xn);
            float e = __expf(-u);
            rp[qq] = xn * __frcp_rn(1.f + e);
        }
        outp[t + r * 256] = res;
    }
}

// ---------------------------------------------------------------------------
extern "C" void kernel_launch(void* const* d_in, const int* in_sizes, int n_in,
                              void* d_out, int out_size, void* d_ws, size_t ws_size,
                              hipStream_t stream) {
    const float* x     = (const float*)d_in[0];
    const float* w_off = (const float*)d_in[1];
    const float* w_dc  = (const float*)d_in[3];
    float* out = (float*)d_out;

    unsigned short* wperm = (unsigned short*)d_ws;                        // 61,440 B
    unsigned short* outpre = (unsigned short*)((char*)d_ws + 61440);      // 16.78 MB f16

    wperm_build<<<120, 256, 0, stream>>>(w_off, w_dc, wperm);
    fused_conv <<<2048, 512, 0, stream>>>(x, wperm,
                                          (const float*)d_in[2],
                                          (const float*)d_in[4], outpre);
    norm_gelu  <<<2048, 256, 0, stream>>>(outpre, out);
}